// Round 1
// baseline (791.929 us; speedup 1.0000x reference)
//
#include <hip/hip_runtime.h>
#include <hip/hip_bf16.h>
#include <cstdint>

typedef __bf16 bf16;
typedef __attribute__((ext_vector_type(8))) __bf16 bf16x8;
typedef __attribute__((ext_vector_type(4))) __bf16 bf16x4;
typedef __attribute__((ext_vector_type(4))) float f32x4;
typedef __attribute__((ext_vector_type(4))) unsigned int u32x4;

#define B_ 4
#define S_ 8192
#define D_ 1024
#define H_ 16
#define HD_ 64
#define W_ 512
#define M_ (B_*S_)   // 32768 rows total

__device__ __forceinline__ void async16(const void* g, void* l) {
  __builtin_amdgcn_global_load_lds(
      (const __attribute__((address_space(1))) unsigned int*)g,
      (__attribute__((address_space(3))) unsigned int*)l, 16, 0, 0);
}

// ---------------- cast f32 -> bf16 ----------------
__global__ void cast_f32_bf16(const float* __restrict__ in, bf16* __restrict__ out, int n4) {
  int i = blockIdx.x * blockDim.x + threadIdx.x;
  int stride = gridDim.x * blockDim.x;
  for (; i < n4; i += stride) {
    f32x4 v = ((const f32x4*)in)[i];
    bf16x4 o = { (bf16)v[0], (bf16)v[1], (bf16)v[2], (bf16)v[3] };
    ((bf16x4*)out)[i] = o;
  }
}

// ---------------- GEMM: C = A(MxK) * Bw(NxK)^T + bias ----------------
// MODE 0: bf16 out row-major   MODE 1: bf16 out V-transposed per batch   MODE 2: f32 out
template<int MODE>
__global__ void __launch_bounds__(256, 2) gemm_bt(
    const bf16* __restrict__ A, const bf16* __restrict__ Bw,
    const float* __restrict__ bias, void* __restrict__ outp, float scale)
{
  constexpr int K = D_, N = D_;
  __shared__ bf16 As[128*32];
  __shared__ bf16 Bs[128*32];
  int bid = blockIdx.x;                       // 2048 blocks, 2048 % 8 == 0
  int nid = (bid & 7) * 256 + (bid >> 3);     // bijective XCD swizzle
  int bm = nid >> 3, bn = nid & 7;
  const int tid = threadIdx.x, lane = tid & 63;
  const int w = tid >> 6, wr = w >> 1, wc = w & 1;
  f32x4 acc[4][4] = {};
  const int r0 = tid >> 2;               // row (0..63) per 16B segment
  const int kbyte = (tid & 3) * 16;      // byte within 64B row
  const char* Ab = (const char*)(A + (size_t)bm * 128 * K);
  const char* Bb = (const char*)(Bw + (size_t)bn * 128 * K);
  for (int kt = 0; kt < K; kt += 32) {
    __syncthreads();
    const size_t cb = (size_t)kt * 2 + kbyte;
    async16(Ab + (size_t)r0      * (K*2) + cb, (char*)As + tid*16);
    async16(Ab + (size_t)(r0+64) * (K*2) + cb, (char*)As + 4096 + tid*16);
    async16(Bb + (size_t)r0      * (K*2) + cb, (char*)Bs + tid*16);
    async16(Bb + (size_t)(r0+64) * (K*2) + cb, (char*)Bs + 4096 + tid*16);
    __syncthreads();
    bf16x8 a[4], b[4];
#pragma unroll
    for (int mi = 0; mi < 4; ++mi)
      a[mi] = *(const bf16x8*)(As + (wr*64 + mi*16 + (lane & 15))*32 + ((lane >> 4)*8));
#pragma unroll
    for (int ni = 0; ni < 4; ++ni)
      b[ni] = *(const bf16x8*)(Bs + (wc*64 + ni*16 + (lane & 15))*32 + ((lane >> 4)*8));
#pragma unroll
    for (int mi = 0; mi < 4; ++mi)
#pragma unroll
      for (int ni = 0; ni < 4; ++ni)
        acc[mi][ni] = __builtin_amdgcn_mfma_f32_16x16x32_bf16(a[mi], b[ni], acc[mi][ni], 0, 0, 0);
  }
  int row0 = bm*128 + wr*64, col0 = bn*128 + wc*64;
  int rsub = (lane >> 4) * 4;
#pragma unroll
  for (int ni = 0; ni < 4; ++ni) {
    int col = col0 + ni*16 + (lane & 15);
    float bz = bias[col];
#pragma unroll
    for (int mi = 0; mi < 4; ++mi) {
#pragma unroll
      for (int r = 0; r < 4; ++r) {
        int row = row0 + mi*16 + rsub + r;
        float v = (acc[mi][ni][r] + bz) * scale;
        if (MODE == 0) {
          ((bf16*)outp)[(size_t)row * N + col] = (bf16)v;
        } else if (MODE == 1) {
          // vt[b][col][s]  (col = h*64+hd), b = row/S, s = row%S
          ((bf16*)outp)[((size_t)(row >> 13) * D_ + col) * S_ + (row & (S_-1))] = (bf16)v;
        } else {
          ((float*)outp)[(size_t)row * N + col] = v;
        }
      }
    }
  }
}

// ---------------- attention ----------------
// grid: B * 16(blocks) * H * 8(q-tiles of 64) = 8192; 256 threads (4 waves x 16 q-rows)
__global__ void __launch_bounds__(256, 2) attn_kernel(
    const bf16* __restrict__ Q, const bf16* __restrict__ Kb,
    const bf16* __restrict__ Vt, bf16* __restrict__ Ao)
{
  __shared__ bf16 Klds[64*64];
  __shared__ bf16 Vlds[64*64];
  __shared__ bf16 Plds[4][16*64];
  int bid = blockIdx.x;
  int qt = bid & 7, h = (bid >> 3) & 15, n = (bid >> 7) & 15, b = bid >> 11;
  int tid = threadIdx.x, lane = tid & 63, w = tid >> 6;
  int qrow = n * W_ + qt * 64 + w * 16;      // wave's 16 query rows start here
  const size_t qoff = ((size_t)(b * S_ + qrow + (lane & 15))) * D_ + h * 64 + ((lane >> 4) * 8);
  bf16x8 qf0 = *(const bf16x8*)(Q + qoff);
  bf16x8 qf1 = *(const bf16x8*)(Q + qoff + 32);
  f32x4 o[4] = {};
  float m_r[4], l_r[4];
#pragma unroll
  for (int r = 0; r < 4; ++r) { m_r[r] = -3.0e38f; l_r[r] = 0.f; }

  const int srow = tid >> 3;           // 0..31 (second pass adds 32)
  const int scol = tid & 7;            // 16B segment within 128B row
  const int c0 = (n == 0) ? 8 : 0;     // block 0: skip padded (masked) keys
  const int sbase = (n - 1) * W_;
  const bf16* Kg = Kb + ((size_t)b * S_) * D_ + h * 64;
  const bf16* Vg = Vt + ((size_t)(b * H_ + h) * HD_) * S_;

  for (int c = c0; c < 16; ++c) {
    int ks = sbase + c * 64;           // global key start (>= 0 always)
    __syncthreads();
    {
      int sw0 = (srow & 7) << 4;       // (srow+32)&7 == srow&7
      u32x4 k0 = *(const u32x4*)(Kg + ((size_t)(ks + srow))      * D_ + scol * 8);
      u32x4 k1 = *(const u32x4*)(Kg + ((size_t)(ks + srow + 32)) * D_ + scol * 8);
      *(u32x4*)((char*)Klds + srow      * 128 + ((scol * 16) ^ sw0)) = k0;
      *(u32x4*)((char*)Klds + (srow+32) * 128 + ((scol * 16) ^ sw0)) = k1;
      u32x4 v0g = *(const u32x4*)(Vg + (size_t)srow      * S_ + ks + scol * 8);
      u32x4 v1g = *(const u32x4*)(Vg + (size_t)(srow+32) * S_ + ks + scol * 8);
      *(u32x4*)((char*)Vlds + srow      * 128 + ((scol * 16) ^ sw0)) = v0g;
      *(u32x4*)((char*)Vlds + (srow+32) * 128 + ((scol * 16) ^ sw0)) = v1g;
    }
    __syncthreads();

    // QK^T: scores tile st[ni]: row=(lane>>4)*4+r (q), col=lane&15 (key in ni-th 16)
    f32x4 st[4];
#pragma unroll
    for (int ni = 0; ni < 4; ++ni) {
      f32x4 z = {};
      int krow = ni*16 + (lane & 15);
      const char* kbase = (const char*)Klds + krow * 128;
      int sw = (krow & 7) << 4;
      bf16x8 kf0 = *(const bf16x8*)(kbase + (((lane >> 4) * 16)      ^ sw));
      bf16x8 kf1 = *(const bf16x8*)(kbase + ((64 + (lane >> 4) * 16) ^ sw));
      z = __builtin_amdgcn_mfma_f32_16x16x32_bf16(qf0, kf0, z, 0, 0, 0);
      z = __builtin_amdgcn_mfma_f32_16x16x32_bf16(qf1, kf1, z, 0, 0, 0);
      st[ni] = z;
    }
    // online softmax
    float mn[4], sc[4], rowsum[4];
#pragma unroll
    for (int r = 0; r < 4; ++r) {
      float mx = fmaxf(fmaxf(st[0][r], st[1][r]), fmaxf(st[2][r], st[3][r]));
#pragma unroll
      for (int off = 1; off < 16; off <<= 1) mx = fmaxf(mx, __shfl_xor(mx, off));
      mn[r] = fmaxf(m_r[r], mx);
      sc[r] = __expf(m_r[r] - mn[r]);
      m_r[r] = mn[r];
      rowsum[r] = 0.f;
    }
#pragma unroll
    for (int ni = 0; ni < 4; ++ni)
#pragma unroll
      for (int r = 0; r < 4; ++r) {
        float p = __expf(st[ni][r] - mn[r]);
        st[ni][r] = p;
        rowsum[r] += p;
      }
#pragma unroll
    for (int r = 0; r < 4; ++r) {
#pragma unroll
      for (int off = 1; off < 16; off <<= 1) rowsum[r] += __shfl_xor(rowsum[r], off);
      l_r[r] = l_r[r] * sc[r] + rowsum[r];
    }
#pragma unroll
    for (int ni = 0; ni < 4; ++ni)
#pragma unroll
      for (int r = 0; r < 4; ++r) o[ni][r] *= sc[r];

    // P -> LDS (bf16, swizzled), then read as MFMA A-fragments
    char* pb = (char*)&Plds[w][0];
#pragma unroll
    for (int ni = 0; ni < 4; ++ni)
#pragma unroll
      for (int r = 0; r < 4; ++r) {
        int prow = (lane >> 4) * 4 + r;
        *(bf16*)(pb + prow * 128 + ((((ni*16 + (lane & 15)) * 2)) ^ ((prow & 7) << 4))) = (bf16)st[ni][r];
      }
    int arow = lane & 15;
    int asw = (arow & 7) << 4;
    bf16x8 pa0 = *(const bf16x8*)(pb + arow * 128 + (((lane >> 4) * 16)      ^ asw));
    bf16x8 pa1 = *(const bf16x8*)(pb + arow * 128 + ((64 + (lane >> 4) * 16) ^ asw));
#pragma unroll
    for (int ni = 0; ni < 4; ++ni) {
      int vrow = ni*16 + (lane & 15);
      const char* vbase = (const char*)Vlds + vrow * 128;
      int vsw = (vrow & 7) << 4;
      bf16x8 vf0 = *(const bf16x8*)(vbase + (((lane >> 4) * 16)      ^ vsw));
      bf16x8 vf1 = *(const bf16x8*)(vbase + ((64 + (lane >> 4) * 16) ^ vsw));
      o[ni] = __builtin_amdgcn_mfma_f32_16x16x32_bf16(pa0, vf0, o[ni], 0, 0, 0);
      o[ni] = __builtin_amdgcn_mfma_f32_16x16x32_bf16(pa1, vf1, o[ni], 0, 0, 0);
    }
  }
  // normalize + store
#pragma unroll
  for (int ni = 0; ni < 4; ++ni)
#pragma unroll
    for (int r = 0; r < 4; ++r) {
      float val = o[ni][r] / l_r[r];
      Ao[((size_t)(b * S_ + qrow + (lane >> 4) * 4 + r)) * D_ + h * 64 + ni*16 + (lane & 15)] = (bf16)val;
    }
}

extern "C" void kernel_launch(void* const* d_in, const int* in_sizes, int n_in,
                              void* d_out, int out_size, void* d_ws, size_t ws_size,
                              hipStream_t stream) {
  const float* x  = (const float*)d_in[0];
  const float* wq = (const float*)d_in[1];
  const float* bq = (const float*)d_in[2];
  const float* wk = (const float*)d_in[3];
  const float* bk = (const float*)d_in[4];
  const float* wv = (const float*)d_in[5];
  const float* bv = (const float*)d_in[6];
  const float* wo = (const float*)d_in[7];
  const float* bo = (const float*)d_in[8];
  float* out = (float*)d_out;

  char* ws = (char*)d_ws;
  const size_t sz = (size_t)M_ * D_ * 2;   // 64 MiB per bf16 activation buffer
  bf16* xb  = (bf16*)(ws + 0*sz);
  bf16* qb  = (bf16*)(ws + 1*sz);
  bf16* kb  = (bf16*)(ws + 2*sz);
  bf16* vt  = (bf16*)(ws + 3*sz);
  bf16* ao  = (bf16*)(ws + 4*sz);
  bf16* wqb = (bf16*)(ws + 5*sz);
  bf16* wkb = wqb + (size_t)D_*D_;
  bf16* wvb = wkb + (size_t)D_*D_;
  bf16* wob = wvb + (size_t)D_*D_;

  cast_f32_bf16<<<2048, 256, 0, stream>>>(x,  xb,  M_*D_/4);
  cast_f32_bf16<<<512,  256, 0, stream>>>(wq, wqb, D_*D_/4);
  cast_f32_bf16<<<512,  256, 0, stream>>>(wk, wkb, D_*D_/4);
  cast_f32_bf16<<<512,  256, 0, stream>>>(wv, wvb, D_*D_/4);
  cast_f32_bf16<<<512,  256, 0, stream>>>(wo, wob, D_*D_/4);

  gemm_bt<0><<<2048, 256, 0, stream>>>(xb, wqb, bq, qb, 0.125f);  // q pre-scaled 1/sqrt(64)
  gemm_bt<0><<<2048, 256, 0, stream>>>(xb, wkb, bk, kb, 1.0f);
  gemm_bt<1><<<2048, 256, 0, stream>>>(xb, wvb, bv, vt, 1.0f);    // V stored transposed

  attn_kernel<<<8192, 256, 0, stream>>>(qb, kb, vt, ao);

  gemm_bt<2><<<2048, 256, 0, stream>>>(ao, wob, bo, out, 1.0f);
}